// Round 11
// baseline (518.236 us; speedup 1.0000x reference)
//
#include <hip/hip_runtime.h>
#include <hip/hip_fp16.h>
#include <math.h>

// Problem constants
#define BB   2
#define CSN  128
#define CDN  128
#define SD   8
#define SH   16
#define SW   16
#define DD   16
#define DH   32
#define DW   32
#define PP   (DD*DH*DW)   // 16384
#define GG   8
#define K3   27
#define OO   648

typedef _Float16 half8 __attribute__((ext_vector_type(8)));
typedef float f32x4 __attribute__((ext_vector_type(4)));
typedef float f32x16 __attribute__((ext_vector_type(16)));

// ---------------------------------------------------------------------------
// Kernel 1: PREP — upsample + weight packs. R24: wtx2 repacked for the
// 5-round x 6-tap schedule: idx = (((g*5+r)*6+m)*4+ob)*64 + l holds, for
// lane l (o = ob*32 + (l&31), kh = l>>5), channels cb..cb+7
// (cb = g*16 + kh*8) of tap r*6+m.  taps >= 27 pack zeros.  61440 half8.
// ---------------------------------------------------------------------------
__global__ __launch_bounds__(256) void prep_kernel(
    const float* __restrict__ src, const float* __restrict__ wof,
    const float* __restrict__ wdcn, half8* __restrict__ uph8,
    half8* __restrict__ woxg, half8* __restrict__ wtx2)
{
    __shared__ float slab[2 * 8 * 16 * 17];
    const int bid = blockIdx.x;
    const int tid = threadIdx.x;

    if (bid < 512) {
        const int zo = bid & 15, pl = bid >> 4;
        const int h = pl & 1, g = (pl >> 1) & 7, b = pl >> 4;
        const int z0 = (zo - 1) >> 1;
        const float fz = (zo & 1) ? 0.25f : 0.75f;
        {
            const int zi = tid >> 7, cc = (tid >> 4) & 7, y = tid & 15;
            const int zsrc = min(max(z0 + zi, 0), SD - 1);
            const float* srow = src +
                (((size_t)(b * CSN + g * 16 + h * 8 + cc) * SD + zsrc) * SH + y) * SW;
            float* drow = &slab[((zi * 8 + cc) * 16 + y) * 17];
            *(float4*)(drow)      = *(const float4*)(srow);
            *(float4*)(drow + 4)  = *(const float4*)(srow + 4);
            *(float4*)(drow + 8)  = *(const float4*)(srow + 8);
            *(float4*)(drow + 12) = *(const float4*)(srow + 12);
        }
        __syncthreads();

        const float wz0 = 1.f - fz, wz1 = fz;
#pragma unroll
        for (int i = 0; i < 4; ++i) {
            const int pp = tid + i * 256;
            const int yo = pp >> 5, xo = pp & 31;
            const int y0 = (yo - 1) >> 1;
            const float fy = (yo & 1) ? 0.25f : 0.75f;
            const int ys0 = max(y0, 0), ys1 = min(y0 + 1, SH - 1);
            const int x0 = (xo - 1) >> 1;
            const float fx = (xo & 1) ? 0.25f : 0.75f;
            const int xs0 = max(x0, 0), xs1 = min(x0 + 1, SW - 1);
            const float w00 = (1.f - fy) * (1.f - fx), w01 = (1.f - fy) * fx;
            const float w10 = fy * (1.f - fx),         w11 = fy * fx;
            const int a00 = ys0 * 17 + xs0, a01 = ys0 * 17 + xs1;
            const int a10 = ys1 * 17 + xs0, a11 = ys1 * 17 + xs1;

            half8 hv;
#pragma unroll
            for (int cc = 0; cc < 8; ++cc) {
                const float* pa = &slab[(cc * 16) * 17];
                const float* pb = &slab[((8 + cc) * 16) * 17];
                const float s0 = w00 * pa[a00] + w01 * pa[a01]
                               + w10 * pa[a10] + w11 * pa[a11];
                const float s1 = w00 * pb[a00] + w01 * pb[a01]
                               + w10 * pb[a10] + w11 * pb[a11];
                hv[cc] = (_Float16)(wz0 * s0 + wz1 * s1);
            }
            uph8[(size_t)pl * PP + zo * 1024 + pp] = hv;
        }
    } else if (bid < 608) {
        const int i = (bid - 512) * 256 + tid;     // < 24576
        const int q = i & 3, lo = (i >> 2) & 15;
        const int t6 = i >> 6;
        const int ot = t6 % 6;
        const int gc0 = t6 / 6;
        const int c0 = gc0 & 7, g = gc0 >> 3;
        const int m = ot * 16 + lo;
        half8 hv;
#pragma unroll
        for (int j = 0; j < 8; ++j) hv[j] = (_Float16)0.0f;
        if (m < 81) {
            const int o = g * 81 + m;
            const int c = c0 * 32 + q * 8;
            const float sc = (c >= 128) ? 2.0f : 1.0f;
            const float* wr = wof + (size_t)o * 256 + c;
#pragma unroll
            for (int j = 0; j < 8; ++j) hv[j] = (_Float16)(wr[j] * sc);
        }
        woxg[i] = hv;
    } else {
        const int i = (bid - 608) * 256 + tid;     // < 61440
        const int l = i & 63;
        const int ob = (i >> 6) & 3;
        const int t = i >> 8;                      // < 240
        const int m = t % 6;
        const int gr = t / 6;                      // g*5 + r, < 40
        const int r = gr % 5, g = gr / 5;
        const int tap = r * 6 + m;
        half8 hv;
#pragma unroll
        for (int j = 0; j < 8; ++j) hv[j] = (_Float16)0.0f;
        if (tap < K3) {
            const int o = ob * 32 + (l & 31);
            const int cb = g * 16 + (l >> 5) * 8;
            const float* wr = wdcn + ((size_t)(o * CSN + cb)) * K3 + tap;
#pragma unroll
            for (int j = 0; j < 8; ++j) hv[j] = (_Float16)wr[(size_t)j * K3];
        }
        wtx2[i] = hv;
    }
}

// ---------------------------------------------------------------------------
// Kernel 2: MEGA — R24 = R22 structure widened to 12 waves (768 thr):
//  * 5 rounds x 6 taps (12 sampling tasks = 6 taps x 2 halves, one/wave);
//    MFMA on waves 0-7 only (32x32x16, 6 K-slices/round) -> waves 8-11
//    run ahead into next-round sampling while 0-7 do MFMA.
//  * 2 blocks/CU still fit (1536 thr, LDS 2x79616 <= 160K) -> 24 waves/CU
//    (75%) vs 16 (50%): the TLP lever for the diagnosed latency-bound
//    regime.  Barriers 8 -> 6 per g.
//  * gather region 9x10x10 -> 8x9x9 (covers |off| ~< 1; ~0.5% exact
//    global fallback), staging 1800 -> 1296 elems.
//  * offls fits inside dbuf1 (13056 >= 11016), no extension.
// LDS: catx 32K | regB 20.25K | dbuf0 12.75K | dbuf1/offls 12.75K = 79616.
// ---------------------------------------------------------------------------
#define REGB_OFF 32768
#define SH2_OFF  53504          // + 648*32
#define DBUF_H8  816            // 12 rows * SROW
#define OFFLS_OFF 66560         // SH2_OFF + 816*16 (dbuf1 base)
#define LDS_TOTAL 79616
#define SROW 68                 // padded sampx row stride (half8)
#define OSTR 68                 // offls row stride (f16)

__global__ __launch_bounds__(768, 6) void mega_kernel(
    const float* __restrict__ dst, const float4* __restrict__ up4,
    const half8* __restrict__ woxg, const half8* __restrict__ wtx2,
    float* __restrict__ out)
{
    __shared__ __align__(16) char ldsraw[LDS_TOTAL];
    half8* catx = (half8*)ldsraw;
    char* regB = ldsraw + REGB_OFF;
    _Float16* offls = (_Float16*)(ldsraw + OFFLS_OFF);
    half8* sampx = (half8*)(ldsraw + SH2_OFF);   // dbuf: +0 / +DBUF_H8

    const int tid = threadIdx.x;
    const int b = blockIdx.y;
    const int cb = blockIdx.x;
    const int X4 = (cb & 7) << 2, Y4 = ((cb >> 3) & 7) << 2, Z4 = (cb >> 6) << 2;

    // ---- phase 0: stage catx with cube columns (co < 32 active) ----
    {
        const int co = tid >> 4, pq = tid & 15;
        const int cz = pq >> 2, cy = pq & 3;
        const int pbase = ((Z4 + cz) << 10) + ((Y4 + cy) << 5) + X4;
        if (co < 16) {                      // dst channels, fp32 -> f16
            const int c = co * 8;
            const float* dp = dst + ((size_t)(b * CDN + c) << 14) + pbase;
            float vv[32];
#pragma unroll
            for (int j = 0; j < 8; ++j)
                *(float4*)&vv[j * 4] = *(const float4*)(dp + ((size_t)j << 14));
#pragma unroll
            for (int i = 0; i < 4; ++i) {
                half8 hh;
#pragma unroll
                for (int j = 0; j < 8; ++j) hh[j] = (_Float16)vv[j * 4 + i];
                catx[co * 64 + pq * 4 + i] = hh;
            }
        } else if (co < 32) {               // upsampled halves: f16 copy
            const int g2 = (co - 16) >> 1, oct = (co - 16) & 1;
            const half8* u8 = (const half8*)up4;
            const size_t base =
                ((size_t)((b * GG + g2) * 2 + oct) << 14) + pbase;
#pragma unroll
            for (int i = 0; i < 4; ++i)
                catx[co * 64 + pq * 4 + i] = u8[base + i];
        }
    }
    __syncthreads();    // catx ready for all g

    const int w = tid >> 6, l = tid & 63, lo = l & 15, q = l >> 4;
    const int t2 = w >> 1, h = w & 1;       // sampling: tap-in-round (0-5), half
    const int ob = w & 3, pt = w >> 2;      // MFMA (w<8): o-block, p-block
    const int kh = l >> 5, c31 = l & 31;    // MFMA lane coords
    const int tp = l;                       // cube column
    const int cz = tp >> 4, cy = (tp >> 2) & 3, cx = tp & 3;
    const int zoA = Z4 + cz, yoA = Y4 + cy, xoA = X4 + cx;

    f32x16 acc;
#pragma unroll
    for (int i = 0; i < 16; ++i) acc[i] = 0.f;

#pragma unroll 1
    for (int g = 0; g < 8; ++g) {
        // (no top-of-g barrier: regB covered by r=4 post-sample barrier;
        //  dbuf1/offls last read by r=3 MFMA which precedes it)

        // ---- region staging: 8x9x9 x 2 halves, parity-swizzled ----
#pragma unroll 1
        for (int c = tid; c < 1296; c += 768) {
            const int hf = c & 1;
            const int v = c >> 1;
            const int zz = v / 81, r2 = v - zz * 81;
            const int yy = r2 / 9, xx = r2 - yy * 9;
            const int vz = min(max(Z4 - 2 + zz, 0), DD - 1);
            const int vy = min(max(Y4 - 2 + yy, 0), DH - 1);
            const int vx = min(max(X4 - 2 + xx, 0), DW - 1);
            const float4 val =
                up4[(size_t)((b * GG + g) * 2 + hf) * PP +
                    (vz << 10) + (vy << 5) + vx];
            const int sw = (xx + yy + zz + hf) & 1;      // parity swizzle
            *(float4*)(regB + v * 32 + sw * 16) = val;
        }

        // ---- phase A: offset mini-GEMM, waves 0-5 ----
        if (w < 6) {
            f32x4 a[4];
#pragma unroll
            for (int ps = 0; ps < 4; ++ps) a[ps] = (f32x4){0.f, 0.f, 0.f, 0.f};
            __builtin_amdgcn_s_setprio(1);
#pragma unroll
            for (int c0 = 0; c0 < 8; ++c0) {
                const half8 A =
                    woxg[(size_t)((((g * 8 + c0) * 6 + w) * 16 + lo) * 4 + q)];
#pragma unroll
                for (int ps = 0; ps < 4; ++ps) {
                    const half8 B = catx[(c0 * 4 + q) * 64 + ps * 16 + lo];
                    a[ps] = __builtin_amdgcn_mfma_f32_16x16x32_f16(A, B, a[ps], 0, 0, 0);
                }
            }
            __builtin_amdgcn_s_setprio(0);
#pragma unroll
            for (int ps = 0; ps < 4; ++ps) {
#pragma unroll
                for (int r = 0; r < 4; ++r) {
                    const int m = w * 16 + q * 4 + r;
                    if (m < 81)
                        offls[m * OSTR + ps * 16 + lo] = (_Float16)a[ps][r];
                }
            }
        }
        __syncthreads();    // staging + offls complete

        // ---- offsets -> registers (safe vs r=1 dbuf1 write: r=0 barrier) ----
        float offv[5][3];
#pragma unroll
        for (int r = 0; r < 5; ++r) {
            const int tap = r * 6 + t2;
            if (tap < K3) {
#pragma unroll
                for (int c = 0; c < 3; ++c)
                    offv[r][c] = (float)offls[(tap * 3 + c) * OSTR + tp];
            }
        }

        // ---- 5 rounds x (sample 6 taps -> A-prefetch -> barrier -> MFMA) ----
#pragma unroll
        for (int r = 0; r < 5; ++r) {
            half8* dbuf = sampx + (r & 1) * DBUF_H8;
            const int tap = r * 6 + t2;
            if (tap < K3) {
                const int kz = tap / 9 - 1;
                const int ky = (tap / 3) % 3 - 1;
                const int kx = (tap % 3) - 1;
                const float z = (float)(zoA + kz) + offv[r][0];
                const float y = (float)(yoA + ky) + offv[r][1];
                const float x = (float)(xoA + kx) + offv[r][2];
                const float zf = floorf(z), yf = floorf(y), xf = floorf(x);
                const float fz = z - zf, fy = y - yf, fx = x - xf;
                const int z0i = (int)zf, y0i = (int)yf, x0i = (int)xf;

                const float wz0 = ((unsigned)z0i < DD) ? 1.f - fz : 0.f;
                const float wz1 = ((unsigned)(z0i + 1) < DD) ? fz : 0.f;
                const float wy0 = ((unsigned)y0i < DH) ? 1.f - fy : 0.f;
                const float wy1 = ((unsigned)(y0i + 1) < DH) ? fy : 0.f;
                const float wx0 = ((unsigned)x0i < DW) ? 1.f - fx : 0.f;
                const float wx1 = ((unsigned)(x0i + 1) < DW) ? fx : 0.f;
                float wcs[8];
                wcs[0] = wz0 * wy0 * wx0; wcs[1] = wz0 * wy0 * wx1;
                wcs[2] = wz0 * wy1 * wx0; wcs[3] = wz0 * wy1 * wx1;
                wcs[4] = wz1 * wy0 * wx0; wcs[5] = wz1 * wy0 * wx1;
                wcs[6] = wz1 * wy1 * wx0; wcs[7] = wz1 * wy1 * wx1;

                const int sz0 = z0i - (Z4 - 2);
                const int sy0 = y0i - (Y4 - 2);
                const int sx0 = x0i - (X4 - 2);

                __align__(16) __half2 acch[4];
#pragma unroll
                for (int rr = 0; rr < 4; ++rr) acch[rr] = __floats2half2_rn(0.f, 0.f);

                if ((unsigned)sz0 <= 6u && (unsigned)sy0 <= 7u &&
                    (unsigned)sx0 <= 7u) {
                    // LDS region gather (8x9x9), parity-swizzled placement
                    const int v000 = (sz0 * 9 + sy0) * 9 + sx0;
                    const int s0 = (sx0 + sy0 + sz0 + h) & 1;   // base parity
                    const int s1 = s0 ^ 1;
                    const int vox[8] = {v000,      v000 + 1,
                                        v000 + 9,  v000 + 10,
                                        v000 + 81, v000 + 82,
                                        v000 + 90, v000 + 91};
                    const int sws[8] = {s0, s1, s1, s0, s1, s0, s0, s1};
                    half8 hv[8];
#pragma unroll
                    for (int ci = 0; ci < 8; ++ci)
                        hv[ci] = *(const half8*)(regB + vox[ci] * 32 + sws[ci] * 16);
#pragma unroll
                    for (int ci = 0; ci < 8; ++ci) {
                        const __half2 wh = __float2half2_rn(wcs[ci]);
                        const __half2* h2 = (const __half2*)&hv[ci];
#pragma unroll
                        for (int rr = 0; rr < 4; ++rr)
                            acch[rr] = __hfma2(h2[rr], wh, acch[rr]);
                    }
                } else {
                    // exact global fallback (rare, ~0.5%)
                    const int iz0 = min(max(z0i, 0), DD - 1);
                    const int iz1 = min(max(z0i + 1, 0), DD - 1);
                    const int iy0 = min(max(y0i, 0), DH - 1);
                    const int iy1 = min(max(y0i + 1, 0), DH - 1);
                    const int ix0 = min(max(x0i, 0), DW - 1);
                    const int ix1 = min(max(x0i + 1, 0), DW - 1);
                    const int v000 = (iz0 << 10) + (iy0 << 5) + ix0;
                    const int dzo = (iz1 - iz0) << 10;
                    const int dyo = (iy1 - iy0) << 5;
                    const int dxo = ix1 - ix0;
                    const int vox[8] = {v000,             v000 + dxo,
                                        v000 + dyo,       v000 + dyo + dxo,
                                        v000 + dzo,       v000 + dzo + dxo,
                                        v000 + dzo + dyo, v000 + dzo + dyo + dxo};
                    const float4* baseF =
                        up4 + (size_t)((b * GG + g) * 2 + h) * PP;
#pragma unroll
                    for (int ci = 0; ci < 8; ++ci) {
                        const float4 u = baseF[vox[ci]];
                        const __half2 wh = __float2half2_rn(wcs[ci]);
                        const __half2* h2 = (const __half2*)&u;
#pragma unroll
                        for (int rr = 0; rr < 4; ++rr)
                            acch[rr] = __hfma2(h2[rr], wh, acch[rr]);
                    }
                }
                dbuf[(t2 * 2 + h) * SROW + tp + (tp >> 4)] = *(half8*)&acch[0];
            }

            // ---- A-prefetch (w<8): latency drains in barrier ----
            half8 Apre[6];
#pragma unroll
            for (int m = 0; m < 6; ++m)
                if (w < 8 && r * 6 + m < K3)
                    Apre[m] = wtx2[(size_t)((((g * 5 + r) * 6 + m) * 4 + ob) * 64 + l)];
            __syncthreads();

            // ---- MFMA (w<8): 32x32x16, wave tile 32o x 32p; 6 K-slices ----
            if (w < 8) {
                __builtin_amdgcn_s_setprio(1);
#pragma unroll
                for (int m = 0; m < 6; ++m) {
                    if (r * 6 + m < K3) {
                        const int colg = pt * 32 + c31;
                        const half8 B = dbuf[(m * 2 + kh) * SROW + colg + (colg >> 4)];
                        acc = __builtin_amdgcn_mfma_f32_32x32x16_f16(Apre[m], B, acc, 0, 0, 0);
                    }
                }
                __builtin_amdgcn_s_setprio(0);
            }
        }
    }

    // ---- epilogue (w<8): ReLU + store (32x32 C/D layout) ----
    if (w < 8) {
        const int cg = pt * 32 + c31;
        const int paddr = ((Z4 + (cg >> 4)) << 10) +
                          ((Y4 + ((cg >> 2) & 3)) << 5) + (X4 + (cg & 3));
#pragma unroll
        for (int reg = 0; reg < 16; ++reg) {
            const int row = (reg & 3) + 8 * (reg >> 2) + 4 * kh;
            const int o = ob * 32 + row;
            out[((size_t)(b * CDN + o) << 14) + paddr] = fmaxf(acc[reg], 0.f);
        }
    }
}

// ---------------------------------------------------------------------------
extern "C" void kernel_launch(void* const* d_in, const int* in_sizes, int n_in,
                              void* d_out, int out_size, void* d_ws, size_t ws_size,
                              hipStream_t stream)
{
    const float* src1x = (const float*)d_in[0];   // [2,128,8,16,16]
    const float* dst2x = (const float*)d_in[1];   // [2,128,16,32,32]
    const float* w_off = (const float*)d_in[2];   // [648,256]
    const float* w_dcn = (const float*)d_in[3];   // [128,128,3,3,3]
    float* out = (float*)d_out;

    char* ws = (char*)d_ws;
    half8* uph8 = (half8*)(ws);                    // 8,388,608 B
    half8* woxg = (half8*)(ws + 8388608);          //   393,216 B
    half8* wtx2 = (half8*)(ws + 8781824);          //   983,040 B

    prep_kernel<<<dim3(848), dim3(256), 0, stream>>>(
        src1x, w_off, w_dcn, uph8, woxg, wtx2);
    mega_kernel<<<dim3(256, BB), dim3(768), 0, stream>>>(
        dst2x, (const float4*)uph8, woxg, wtx2, out);
}

// Round 12
// 262.918 us; speedup vs baseline: 1.9711x; 1.9711x over previous
//
#include <hip/hip_runtime.h>
#include <hip/hip_fp16.h>
#include <math.h>

// Problem constants
#define BB   2
#define CSN  128
#define CDN  128
#define SD   8
#define SH   16
#define SW   16
#define DD   16
#define DH   32
#define DW   32
#define PP   (DD*DH*DW)   // 16384
#define GG   8
#define K3   27
#define OO   648

typedef _Float16 half8 __attribute__((ext_vector_type(8)));
typedef float f32x4 __attribute__((ext_vector_type(4)));
typedef float f32x16 __attribute__((ext_vector_type(16)));

// ---------------------------------------------------------------------------
// Kernel 1: PREP — upsample + weight packs (R24 version: wtx2 packed for
// the 5-round x 6-tap schedule; taps >= 27 pack zeros; 61440 half8).
// ---------------------------------------------------------------------------
__global__ __launch_bounds__(256) void prep_kernel(
    const float* __restrict__ src, const float* __restrict__ wof,
    const float* __restrict__ wdcn, half8* __restrict__ uph8,
    half8* __restrict__ woxg, half8* __restrict__ wtx2)
{
    __shared__ float slab[2 * 8 * 16 * 17];
    const int bid = blockIdx.x;
    const int tid = threadIdx.x;

    if (bid < 512) {
        const int zo = bid & 15, pl = bid >> 4;
        const int h = pl & 1, g = (pl >> 1) & 7, b = pl >> 4;
        const int z0 = (zo - 1) >> 1;
        const float fz = (zo & 1) ? 0.25f : 0.75f;
        {
            const int zi = tid >> 7, cc = (tid >> 4) & 7, y = tid & 15;
            const int zsrc = min(max(z0 + zi, 0), SD - 1);
            const float* srow = src +
                (((size_t)(b * CSN + g * 16 + h * 8 + cc) * SD + zsrc) * SH + y) * SW;
            float* drow = &slab[((zi * 8 + cc) * 16 + y) * 17];
            *(float4*)(drow)      = *(const float4*)(srow);
            *(float4*)(drow + 4)  = *(const float4*)(srow + 4);
            *(float4*)(drow + 8)  = *(const float4*)(srow + 8);
            *(float4*)(drow + 12) = *(const float4*)(srow + 12);
        }
        __syncthreads();

        const float wz0 = 1.f - fz, wz1 = fz;
#pragma unroll
        for (int i = 0; i < 4; ++i) {
            const int pp = tid + i * 256;
            const int yo = pp >> 5, xo = pp & 31;
            const int y0 = (yo - 1) >> 1;
            const float fy = (yo & 1) ? 0.25f : 0.75f;
            const int ys0 = max(y0, 0), ys1 = min(y0 + 1, SH - 1);
            const int x0 = (xo - 1) >> 1;
            const float fx = (xo & 1) ? 0.25f : 0.75f;
            const int xs0 = max(x0, 0), xs1 = min(x0 + 1, SW - 1);
            const float w00 = (1.f - fy) * (1.f - fx), w01 = (1.f - fy) * fx;
            const float w10 = fy * (1.f - fx),         w11 = fy * fx;
            const int a00 = ys0 * 17 + xs0, a01 = ys0 * 17 + xs1;
            const int a10 = ys1 * 17 + xs0, a11 = ys1 * 17 + xs1;

            half8 hv;
#pragma unroll
            for (int cc = 0; cc < 8; ++cc) {
                const float* pa = &slab[(cc * 16) * 17];
                const float* pb = &slab[((8 + cc) * 16) * 17];
                const float s0 = w00 * pa[a00] + w01 * pa[a01]
                               + w10 * pa[a10] + w11 * pa[a11];
                const float s1 = w00 * pb[a00] + w01 * pb[a01]
                               + w10 * pb[a10] + w11 * pb[a11];
                hv[cc] = (_Float16)(wz0 * s0 + wz1 * s1);
            }
            uph8[(size_t)pl * PP + zo * 1024 + pp] = hv;
        }
    } else if (bid < 608) {
        const int i = (bid - 512) * 256 + tid;     // < 24576
        const int q = i & 3, lo = (i >> 2) & 15;
        const int t6 = i >> 6;
        const int ot = t6 % 6;
        const int gc0 = t6 / 6;
        const int c0 = gc0 & 7, g = gc0 >> 3;
        const int m = ot * 16 + lo;
        half8 hv;
#pragma unroll
        for (int j = 0; j < 8; ++j) hv[j] = (_Float16)0.0f;
        if (m < 81) {
            const int o = g * 81 + m;
            const int c = c0 * 32 + q * 8;
            const float sc = (c >= 128) ? 2.0f : 1.0f;
            const float* wr = wof + (size_t)o * 256 + c;
#pragma unroll
            for (int j = 0; j < 8; ++j) hv[j] = (_Float16)(wr[j] * sc);
        }
        woxg[i] = hv;
    } else {
        const int i = (bid - 608) * 256 + tid;     // < 61440
        const int l = i & 63;
        const int ob = (i >> 6) & 3;
        const int t = i >> 8;                      // < 240
        const int m = t % 6;
        const int gr = t / 6;                      // g*5 + r, < 40
        const int r = gr % 5, g = gr / 5;
        const int tap = r * 6 + m;
        half8 hv;
#pragma unroll
        for (int j = 0; j < 8; ++j) hv[j] = (_Float16)0.0f;
        if (tap < K3) {
            const int o = ob * 32 + (l & 31);
            const int cb = g * 16 + (l >> 5) * 8;
            const float* wr = wdcn + ((size_t)(o * CSN + cb)) * K3 + tap;
#pragma unroll
            for (int j = 0; j < 8; ++j) hv[j] = (_Float16)wr[(size_t)j * K3];
        }
        wtx2[i] = hv;
    }
}

// ---------------------------------------------------------------------------
// Kernel 2: MEGA — R25 = R24 structure (5x6 schedule, 768 thr, 8x9x9
// region; proven correct, occupancy 62%) with the spill fixed:
//  * __launch_bounds__(768, 4): VGPR cap 128 (R24's (768,6) starved the
//    allocator to 40 VGPRs -> f32x16 acc spilled -> 1.4 GB scratch).
//  * Apre[6] prefetch deleted (-24 VGPR): A loads directly from
//    L2-resident wtx2 inside the MFMA loop; at 24 waves/CU the latency
//    is TLP-absorbed.  Target natural allocation 64-84 <= 85 so the HW
//    fits 2 blocks/CU (24 waves, 75%).
// LDS: catx 32K | regB 20.25K | dbuf0 12.75K | dbuf1/offls 12.75K = 79616.
// ---------------------------------------------------------------------------
#define REGB_OFF 32768
#define SH2_OFF  53504          // + 648*32
#define DBUF_H8  816            // 12 rows * SROW
#define OFFLS_OFF 66560         // SH2_OFF + 816*16 (dbuf1 base)
#define LDS_TOTAL 79616
#define SROW 68                 // padded sampx row stride (half8)
#define OSTR 68                 // offls row stride (f16)

__global__ __launch_bounds__(768, 4) void mega_kernel(
    const float* __restrict__ dst, const float4* __restrict__ up4,
    const half8* __restrict__ woxg, const half8* __restrict__ wtx2,
    float* __restrict__ out)
{
    __shared__ __align__(16) char ldsraw[LDS_TOTAL];
    half8* catx = (half8*)ldsraw;
    char* regB = ldsraw + REGB_OFF;
    _Float16* offls = (_Float16*)(ldsraw + OFFLS_OFF);
    half8* sampx = (half8*)(ldsraw + SH2_OFF);   // dbuf: +0 / +DBUF_H8

    const int tid = threadIdx.x;
    const int b = blockIdx.y;
    const int cb = blockIdx.x;
    const int X4 = (cb & 7) << 2, Y4 = ((cb >> 3) & 7) << 2, Z4 = (cb >> 6) << 2;

    // ---- phase 0: stage catx with cube columns (co < 32 active) ----
    {
        const int co = tid >> 4, pq = tid & 15;
        const int cz = pq >> 2, cy = pq & 3;
        const int pbase = ((Z4 + cz) << 10) + ((Y4 + cy) << 5) + X4;
        if (co < 16) {                      // dst channels, fp32 -> f16
            const int c = co * 8;
            const float* dp = dst + ((size_t)(b * CDN + c) << 14) + pbase;
            float vv[32];
#pragma unroll
            for (int j = 0; j < 8; ++j)
                *(float4*)&vv[j * 4] = *(const float4*)(dp + ((size_t)j << 14));
#pragma unroll
            for (int i = 0; i < 4; ++i) {
                half8 hh;
#pragma unroll
                for (int j = 0; j < 8; ++j) hh[j] = (_Float16)vv[j * 4 + i];
                catx[co * 64 + pq * 4 + i] = hh;
            }
        } else if (co < 32) {               // upsampled halves: f16 copy
            const int g2 = (co - 16) >> 1, oct = (co - 16) & 1;
            const half8* u8 = (const half8*)up4;
            const size_t base =
                ((size_t)((b * GG + g2) * 2 + oct) << 14) + pbase;
#pragma unroll
            for (int i = 0; i < 4; ++i)
                catx[co * 64 + pq * 4 + i] = u8[base + i];
        }
    }
    __syncthreads();    // catx ready for all g

    const int w = tid >> 6, l = tid & 63, lo = l & 15, q = l >> 4;
    const int t2 = w >> 1, h = w & 1;       // sampling: tap-in-round (0-5), half
    const int ob = w & 3, pt = w >> 2;      // MFMA (w<8): o-block, p-block
    const int kh = l >> 5, c31 = l & 31;    // MFMA lane coords
    const int tp = l;                       // cube column
    const int cz = tp >> 4, cy = (tp >> 2) & 3, cx = tp & 3;
    const int zoA = Z4 + cz, yoA = Y4 + cy, xoA = X4 + cx;

    f32x16 acc;
#pragma unroll
    for (int i = 0; i < 16; ++i) acc[i] = 0.f;

#pragma unroll 1
    for (int g = 0; g < 8; ++g) {
        // (no top-of-g barrier: regB covered by r=4 post-sample barrier;
        //  dbuf1/offls last read by r=3 MFMA which precedes it)

        // ---- region staging: 8x9x9 x 2 halves, parity-swizzled ----
#pragma unroll 1
        for (int c = tid; c < 1296; c += 768) {
            const int hf = c & 1;
            const int v = c >> 1;
            const int zz = v / 81, r2 = v - zz * 81;
            const int yy = r2 / 9, xx = r2 - yy * 9;
            const int vz = min(max(Z4 - 2 + zz, 0), DD - 1);
            const int vy = min(max(Y4 - 2 + yy, 0), DH - 1);
            const int vx = min(max(X4 - 2 + xx, 0), DW - 1);
            const float4 val =
                up4[(size_t)((b * GG + g) * 2 + hf) * PP +
                    (vz << 10) + (vy << 5) + vx];
            const int sw = (xx + yy + zz + hf) & 1;      // parity swizzle
            *(float4*)(regB + v * 32 + sw * 16) = val;
        }

        // ---- phase A: offset mini-GEMM, waves 0-5 ----
        if (w < 6) {
            f32x4 a[4];
#pragma unroll
            for (int ps = 0; ps < 4; ++ps) a[ps] = (f32x4){0.f, 0.f, 0.f, 0.f};
            __builtin_amdgcn_s_setprio(1);
#pragma unroll
            for (int c0 = 0; c0 < 8; ++c0) {
                const half8 A =
                    woxg[(size_t)((((g * 8 + c0) * 6 + w) * 16 + lo) * 4 + q)];
#pragma unroll
                for (int ps = 0; ps < 4; ++ps) {
                    const half8 B = catx[(c0 * 4 + q) * 64 + ps * 16 + lo];
                    a[ps] = __builtin_amdgcn_mfma_f32_16x16x32_f16(A, B, a[ps], 0, 0, 0);
                }
            }
            __builtin_amdgcn_s_setprio(0);
#pragma unroll
            for (int ps = 0; ps < 4; ++ps) {
#pragma unroll
                for (int r = 0; r < 4; ++r) {
                    const int m = w * 16 + q * 4 + r;
                    if (m < 81)
                        offls[m * OSTR + ps * 16 + lo] = (_Float16)a[ps][r];
                }
            }
        }
        __syncthreads();    // staging + offls complete

        // ---- offsets -> registers (safe vs r=1 dbuf1 write: r=0 barrier) ----
        float offv[5][3];
#pragma unroll
        for (int r = 0; r < 5; ++r) {
            const int tap = r * 6 + t2;
            if (tap < K3) {
#pragma unroll
                for (int c = 0; c < 3; ++c)
                    offv[r][c] = (float)offls[(tap * 3 + c) * OSTR + tp];
            }
        }

        // ---- 5 rounds x (sample 6 taps -> barrier -> MFMA) ----
#pragma unroll
        for (int r = 0; r < 5; ++r) {
            half8* dbuf = sampx + (r & 1) * DBUF_H8;
            const int tap = r * 6 + t2;
            if (tap < K3) {
                const int kz = tap / 9 - 1;
                const int ky = (tap / 3) % 3 - 1;
                const int kx = (tap % 3) - 1;
                const float z = (float)(zoA + kz) + offv[r][0];
                const float y = (float)(yoA + ky) + offv[r][1];
                const float x = (float)(xoA + kx) + offv[r][2];
                const float zf = floorf(z), yf = floorf(y), xf = floorf(x);
                const float fz = z - zf, fy = y - yf, fx = x - xf;
                const int z0i = (int)zf, y0i = (int)yf, x0i = (int)xf;

                const float wz0 = ((unsigned)z0i < DD) ? 1.f - fz : 0.f;
                const float wz1 = ((unsigned)(z0i + 1) < DD) ? fz : 0.f;
                const float wy0 = ((unsigned)y0i < DH) ? 1.f - fy : 0.f;
                const float wy1 = ((unsigned)(y0i + 1) < DH) ? fy : 0.f;
                const float wx0 = ((unsigned)x0i < DW) ? 1.f - fx : 0.f;
                const float wx1 = ((unsigned)(x0i + 1) < DW) ? fx : 0.f;
                float wcs[8];
                wcs[0] = wz0 * wy0 * wx0; wcs[1] = wz0 * wy0 * wx1;
                wcs[2] = wz0 * wy1 * wx0; wcs[3] = wz0 * wy1 * wx1;
                wcs[4] = wz1 * wy0 * wx0; wcs[5] = wz1 * wy0 * wx1;
                wcs[6] = wz1 * wy1 * wx0; wcs[7] = wz1 * wy1 * wx1;

                const int sz0 = z0i - (Z4 - 2);
                const int sy0 = y0i - (Y4 - 2);
                const int sx0 = x0i - (X4 - 2);

                __align__(16) __half2 acch[4];
#pragma unroll
                for (int rr = 0; rr < 4; ++rr) acch[rr] = __floats2half2_rn(0.f, 0.f);

                if ((unsigned)sz0 <= 6u && (unsigned)sy0 <= 7u &&
                    (unsigned)sx0 <= 7u) {
                    // LDS region gather (8x9x9), parity-swizzled placement
                    const int v000 = (sz0 * 9 + sy0) * 9 + sx0;
                    const int s0 = (sx0 + sy0 + sz0 + h) & 1;   // base parity
                    const int s1 = s0 ^ 1;
                    const int vox[8] = {v000,      v000 + 1,
                                        v000 + 9,  v000 + 10,
                                        v000 + 81, v000 + 82,
                                        v000 + 90, v000 + 91};
                    const int sws[8] = {s0, s1, s1, s0, s1, s0, s0, s1};
                    half8 hv[8];
#pragma unroll
                    for (int ci = 0; ci < 8; ++ci)
                        hv[ci] = *(const half8*)(regB + vox[ci] * 32 + sws[ci] * 16);
#pragma unroll
                    for (int ci = 0; ci < 8; ++ci) {
                        const __half2 wh = __float2half2_rn(wcs[ci]);
                        const __half2* h2 = (const __half2*)&hv[ci];
#pragma unroll
                        for (int rr = 0; rr < 4; ++rr)
                            acch[rr] = __hfma2(h2[rr], wh, acch[rr]);
                    }
                } else {
                    // exact global fallback (rare, ~0.5%)
                    const int iz0 = min(max(z0i, 0), DD - 1);
                    const int iz1 = min(max(z0i + 1, 0), DD - 1);
                    const int iy0 = min(max(y0i, 0), DH - 1);
                    const int iy1 = min(max(y0i + 1, 0), DH - 1);
                    const int ix0 = min(max(x0i, 0), DW - 1);
                    const int ix1 = min(max(x0i + 1, 0), DW - 1);
                    const int v000 = (iz0 << 10) + (iy0 << 5) + ix0;
                    const int dzo = (iz1 - iz0) << 10;
                    const int dyo = (iy1 - iy0) << 5;
                    const int dxo = ix1 - ix0;
                    const int vox[8] = {v000,             v000 + dxo,
                                        v000 + dyo,       v000 + dyo + dxo,
                                        v000 + dzo,       v000 + dzo + dxo,
                                        v000 + dzo + dyo, v000 + dzo + dyo + dxo};
                    const float4* baseF =
                        up4 + (size_t)((b * GG + g) * 2 + h) * PP;
#pragma unroll
                    for (int ci = 0; ci < 8; ++ci) {
                        const float4 u = baseF[vox[ci]];
                        const __half2 wh = __float2half2_rn(wcs[ci]);
                        const __half2* h2 = (const __half2*)&u;
#pragma unroll
                        for (int rr = 0; rr < 4; ++rr)
                            acch[rr] = __hfma2(h2[rr], wh, acch[rr]);
                    }
                }
                dbuf[(t2 * 2 + h) * SROW + tp + (tp >> 4)] = *(half8*)&acch[0];
            }
            __syncthreads();

            // ---- MFMA (w<8): 32x32x16; A direct from L2-resident wtx2 ----
            if (w < 8) {
                __builtin_amdgcn_s_setprio(1);
#pragma unroll
                for (int m = 0; m < 6; ++m) {
                    if (r * 6 + m < K3) {
                        const half8 A = wtx2[(size_t)(
                            (((g * 5 + r) * 6 + m) * 4 + ob) * 64 + l)];
                        const int colg = pt * 32 + c31;
                        const half8 B = dbuf[(m * 2 + kh) * SROW + colg + (colg >> 4)];
                        acc = __builtin_amdgcn_mfma_f32_32x32x16_f16(A, B, acc, 0, 0, 0);
                    }
                }
                __builtin_amdgcn_s_setprio(0);
            }
        }
    }

    // ---- epilogue (w<8): ReLU + store (32x32 C/D layout) ----
    if (w < 8) {
        const int cg = pt * 32 + c31;
        const int paddr = ((Z4 + (cg >> 4)) << 10) +
                          ((Y4 + ((cg >> 2) & 3)) << 5) + (X4 + (cg & 3));
#pragma unroll
        for (int reg = 0; reg < 16; ++reg) {
            const int row = (reg & 3) + 8 * (reg >> 2) + 4 * kh;
            const int o = ob * 32 + row;
            out[((size_t)(b * CDN + o) << 14) + paddr] = fmaxf(acc[reg], 0.f);
        }
    }
}

// ---------------------------------------------------------------------------
extern "C" void kernel_launch(void* const* d_in, const int* in_sizes, int n_in,
                              void* d_out, int out_size, void* d_ws, size_t ws_size,
                              hipStream_t stream)
{
    const float* src1x = (const float*)d_in[0];   // [2,128,8,16,16]
    const float* dst2x = (const float*)d_in[1];   // [2,128,16,32,32]
    const float* w_off = (const float*)d_in[2];   // [648,256]
    const float* w_dcn = (const float*)d_in[3];   // [128,128,3,3,3]
    float* out = (float*)d_out;

    char* ws = (char*)d_ws;
    half8* uph8 = (half8*)(ws);                    // 8,388,608 B
    half8* woxg = (half8*)(ws + 8388608);          //   393,216 B
    half8* wtx2 = (half8*)(ws + 8781824);          //   983,040 B

    prep_kernel<<<dim3(848), dim3(256), 0, stream>>>(
        src1x, w_off, w_dcn, uph8, woxg, wtx2);
    mega_kernel<<<dim3(256, BB), dim3(768), 0, stream>>>(
        dst2x, (const float4*)uph8, woxg, wtx2, out);
}

// Round 13
// 194.856 us; speedup vs baseline: 2.6596x; 1.3493x over previous
//
#include <hip/hip_runtime.h>
#include <hip/hip_fp16.h>
#include <math.h>

// Problem constants
#define BB   2
#define CSN  128
#define CDN  128
#define SD   8
#define SH   16
#define SW   16
#define DD   16
#define DH   32
#define DW   32
#define PP   (DD*DH*DW)   // 16384
#define GG   8
#define K3   27
#define OO   648

typedef _Float16 half8 __attribute__((ext_vector_type(8)));
typedef float f32x4 __attribute__((ext_vector_type(4)));
typedef float f32x16 __attribute__((ext_vector_type(16)));

// ---------------------------------------------------------------------------
// Kernel 1: PREP — upsample + weight packs. wtx2 packed for the 32x32x16
// A-fragment layout: element i = ((g*7+r)*4+m)*256 + ob*64 + l holds, for
// lane l (o = ob*32 + (l&31), h = l>>5), channels cb..cb+7 (cb = g*16+h*8)
// of tap r*4+m.  tap 27 (r=6,m=3) packs zeros.
// ---------------------------------------------------------------------------
__global__ __launch_bounds__(256) void prep_kernel(
    const float* __restrict__ src, const float* __restrict__ wof,
    const float* __restrict__ wdcn, half8* __restrict__ uph8,
    half8* __restrict__ woxg, half8* __restrict__ wtx2)
{
    __shared__ float slab[2 * 8 * 16 * 17];
    const int bid = blockIdx.x;
    const int tid = threadIdx.x;

    if (bid < 512) {
        const int zo = bid & 15, pl = bid >> 4;
        const int h = pl & 1, g = (pl >> 1) & 7, b = pl >> 4;
        const int z0 = (zo - 1) >> 1;
        const float fz = (zo & 1) ? 0.25f : 0.75f;
        {
            const int zi = tid >> 7, cc = (tid >> 4) & 7, y = tid & 15;
            const int zsrc = min(max(z0 + zi, 0), SD - 1);
            const float* srow = src +
                (((size_t)(b * CSN + g * 16 + h * 8 + cc) * SD + zsrc) * SH + y) * SW;
            float* drow = &slab[((zi * 8 + cc) * 16 + y) * 17];
            *(float4*)(drow)      = *(const float4*)(srow);
            *(float4*)(drow + 4)  = *(const float4*)(srow + 4);
            *(float4*)(drow + 8)  = *(const float4*)(srow + 8);
            *(float4*)(drow + 12) = *(const float4*)(srow + 12);
        }
        __syncthreads();

        const float wz0 = 1.f - fz, wz1 = fz;
#pragma unroll
        for (int i = 0; i < 4; ++i) {
            const int pp = tid + i * 256;
            const int yo = pp >> 5, xo = pp & 31;
            const int y0 = (yo - 1) >> 1;
            const float fy = (yo & 1) ? 0.25f : 0.75f;
            const int ys0 = max(y0, 0), ys1 = min(y0 + 1, SH - 1);
            const int x0 = (xo - 1) >> 1;
            const float fx = (xo & 1) ? 0.25f : 0.75f;
            const int xs0 = max(x0, 0), xs1 = min(x0 + 1, SW - 1);
            const float w00 = (1.f - fy) * (1.f - fx), w01 = (1.f - fy) * fx;
            const float w10 = fy * (1.f - fx),         w11 = fy * fx;
            const int a00 = ys0 * 17 + xs0, a01 = ys0 * 17 + xs1;
            const int a10 = ys1 * 17 + xs0, a11 = ys1 * 17 + xs1;

            half8 hv;
#pragma unroll
            for (int cc = 0; cc < 8; ++cc) {
                const float* pa = &slab[(cc * 16) * 17];
                const float* pb = &slab[((8 + cc) * 16) * 17];
                const float s0 = w00 * pa[a00] + w01 * pa[a01]
                               + w10 * pa[a10] + w11 * pa[a11];
                const float s1 = w00 * pb[a00] + w01 * pb[a01]
                               + w10 * pb[a10] + w11 * pb[a11];
                hv[cc] = (_Float16)(wz0 * s0 + wz1 * s1);
            }
            uph8[(size_t)pl * PP + zo * 1024 + pp] = hv;
        }
    } else if (bid < 608) {
        const int i = (bid - 512) * 256 + tid;     // < 24576
        const int q = i & 3, lo = (i >> 2) & 15;
        const int t6 = i >> 6;
        const int ot = t6 % 6;
        const int gc0 = t6 / 6;
        const int c0 = gc0 & 7, g = gc0 >> 3;
        const int m = ot * 16 + lo;
        half8 hv;
#pragma unroll
        for (int j = 0; j < 8; ++j) hv[j] = (_Float16)0.0f;
        if (m < 81) {
            const int o = g * 81 + m;
            const int c = c0 * 32 + q * 8;
            const float sc = (c >= 128) ? 2.0f : 1.0f;
            const float* wr = wof + (size_t)o * 256 + c;
#pragma unroll
            for (int j = 0; j < 8; ++j) hv[j] = (_Float16)(wr[j] * sc);
        }
        woxg[i] = hv;
    } else {
        const int i = (bid - 608) * 256 + tid;     // < 57344
        const int l = i & 63;
        const int ob = (i >> 6) & 3;
        const int m = (i >> 8) & 3;
        const int gr = i >> 10;                    // g*7 + r, < 56
        const int r = gr % 7, g = gr / 7;
        const int tap = r * 4 + m;
        half8 hv;
#pragma unroll
        for (int j = 0; j < 8; ++j) hv[j] = (_Float16)0.0f;
        if (tap < K3) {
            const int o = ob * 32 + (l & 31);
            const int cb = g * 16 + (l >> 5) * 8;
            const float* wr = wdcn + ((size_t)(o * CSN + cb)) * K3 + tap;
#pragma unroll
            for (int j = 0; j < 8; ++j) hv[j] = (_Float16)wr[(size_t)j * K3];
        }
        wtx2[i] = hv;
    }
}

// ---------------------------------------------------------------------------
// Kernel 2: MEGA — R26 = R22 byte-exact (session best: 133.4 us mega,
// 192.9 us total).  Structure: 4x4x4 cube/block, 512 thr, 2 blocks/CU;
// VGPR-roundtrip region staging (9x10x10, parity-swizzled); offls on
// dbuf1 (barrier-reduced schedule, 65 barriers/block); offls stride 68;
// A-prefetch above the round barrier; setprio around MFMA clusters;
// DCN GEMM as 32x32x16 (4 B-reads/wave/round).
// Dead ends proven this session (do NOT retry): XCD swizzle on this
// fully-resident grid (R15), global_load_lds for scattered halo staging
// (R20), register state across divergent phase-A (R18), g-split partials
// (R14), 768-thr wide blocks (R24/R25: spill then 1-block residency).
// LDS: catx 32K | regB 28.8K | dbuf0 8.5K | dbuf1+ext = offls 11K
//   => 81296 B, 2 blocks/CU.
// ---------------------------------------------------------------------------
#define REGB_OFF 32768
#define SH2_OFF  61568
#define OFFLS_OFF 70272         // SH2_OFF + 544*16 (dbuf1 base)
#define LDS_TOTAL 81296
#define SROW 68                 // padded sampx row stride (half8)
#define OSTR 68                 // offls row stride (f16)

__global__ __launch_bounds__(512, 4) void mega_kernel(
    const float* __restrict__ dst, const float4* __restrict__ up4,
    const half8* __restrict__ woxg, const half8* __restrict__ wtx2,
    float* __restrict__ out)
{
    __shared__ __align__(16) char ldsraw[LDS_TOTAL];
    half8* catx = (half8*)ldsraw;
    char* regB = ldsraw + REGB_OFF;
    _Float16* offls = (_Float16*)(ldsraw + OFFLS_OFF);
    half8* sampx = (half8*)(ldsraw + SH2_OFF);   // dbuf: +0 / +544 half8

    const int tid = threadIdx.x;
    const int b = blockIdx.y;
    const int cb = blockIdx.x;
    const int X4 = (cb & 7) << 2, Y4 = ((cb >> 3) & 7) << 2, Z4 = (cb >> 6) << 2;

    // ---- phase 0: stage catx with cube columns ----
    {
        const int co = tid >> 4, pq = tid & 15;
        const int cz = pq >> 2, cy = pq & 3;
        const int pbase = ((Z4 + cz) << 10) + ((Y4 + cy) << 5) + X4;
        if (co < 16) {                      // dst channels, fp32 -> f16
            const int c = co * 8;
            const float* dp = dst + ((size_t)(b * CDN + c) << 14) + pbase;
            float vv[32];
#pragma unroll
            for (int j = 0; j < 8; ++j)
                *(float4*)&vv[j * 4] = *(const float4*)(dp + ((size_t)j << 14));
#pragma unroll
            for (int i = 0; i < 4; ++i) {
                half8 hh;
#pragma unroll
                for (int j = 0; j < 8; ++j) hh[j] = (_Float16)vv[j * 4 + i];
                catx[co * 64 + pq * 4 + i] = hh;
            }
        } else {                            // upsampled halves: f16 copy
            const int g2 = (co - 16) >> 1, oct = (co - 16) & 1;
            const half8* u8 = (const half8*)up4;
            const size_t base =
                ((size_t)((b * GG + g2) * 2 + oct) << 14) + pbase;
#pragma unroll
            for (int i = 0; i < 4; ++i)
                catx[co * 64 + pq * 4 + i] = u8[base + i];
        }
    }
    __syncthreads();    // catx ready for all g

    const int w = tid >> 6, l = tid & 63, lo = l & 15, q = l >> 4;
    const int t2 = w >> 1, h = w & 1;       // sampling: tap-in-round, ch-half
    const int ob = w & 3, pt = w >> 2;      // MFMA: o-block, p-block
    const int kh = l >> 5, c31 = l & 31;    // MFMA lane coords
    const int tp = l;                       // cube column
    const int cz = tp >> 4, cy = (tp >> 2) & 3, cx = tp & 3;
    const int zoA = Z4 + cz, yoA = Y4 + cy, xoA = X4 + cx;

    f32x16 acc;
#pragma unroll
    for (int i = 0; i < 16; ++i) acc[i] = 0.f;

#pragma unroll 1
    for (int g = 0; g < 8; ++g) {
        // (no top-of-g barrier: regB free after r=6 post-sample barrier;
        //  dbuf1/offls last read by r=5 MFMA which precedes it)

        // ---- region staging: interleaved (hf = c&1), parity-swizzled ----
#pragma unroll 1
        for (int c = tid; c < 1800; c += 512) {
            const int hf = c & 1;
            const int v = c >> 1;
            const int zz = v / 100, r2 = v - zz * 100;
            const int yy = r2 / 10, xx = r2 - yy * 10;
            const int vz = min(max(Z4 - 3 + zz, 0), DD - 1);
            const int vy = min(max(Y4 - 3 + yy, 0), DH - 1);
            const int vx = min(max(X4 - 3 + xx, 0), DW - 1);
            const float4 val =
                up4[(size_t)((b * GG + g) * 2 + hf) * PP +
                    (vz << 10) + (vy << 5) + vx];
            const int sw = (xx + yy + zz + hf) & 1;      // parity swizzle
            *(float4*)(regB + v * 32 + sw * 16) = val;
        }

        // ---- phase A: offset mini-GEMM, A reused across all 4 ps ----
        if (w < 6) {
            f32x4 a[4];
#pragma unroll
            for (int ps = 0; ps < 4; ++ps) a[ps] = (f32x4){0.f, 0.f, 0.f, 0.f};
            __builtin_amdgcn_s_setprio(1);
#pragma unroll
            for (int c0 = 0; c0 < 8; ++c0) {
                const half8 A =
                    woxg[(size_t)((((g * 8 + c0) * 6 + w) * 16 + lo) * 4 + q)];
#pragma unroll
                for (int ps = 0; ps < 4; ++ps) {
                    const half8 B = catx[(c0 * 4 + q) * 64 + ps * 16 + lo];
                    a[ps] = __builtin_amdgcn_mfma_f32_16x16x32_f16(A, B, a[ps], 0, 0, 0);
                }
            }
            __builtin_amdgcn_s_setprio(0);
#pragma unroll
            for (int ps = 0; ps < 4; ++ps) {
#pragma unroll
                for (int r = 0; r < 4; ++r) {
                    const int m = w * 16 + q * 4 + r;
                    if (m < 81)
                        offls[m * OSTR + ps * 16 + lo] = (_Float16)a[ps][r];
                }
            }
        }
        __syncthreads();    // staging + offls complete

        // ---- offsets -> registers (safe vs r=1 dbuf1 write: r=0 barrier) ----
        float offv[7][3];
#pragma unroll
        for (int r = 0; r < 7; ++r) {
            const int tap = r * 4 + t2;
            if (tap < K3) {
#pragma unroll
                for (int c = 0; c < 3; ++c)
                    offv[r][c] = (float)offls[(tap * 3 + c) * OSTR + tp];
            }
        }
        // (no post-offv barrier: r=0 writes dbuf0, disjoint from offls)

        // ---- 7 rounds x (sample 4 taps -> A-prefetch -> barrier -> MFMA) ----
#pragma unroll
        for (int r = 0; r < 7; ++r) {
            half8* dbuf = sampx + (r & 1) * 544;
            const int tap = r * 4 + t2;
            if (tap < K3) {
                const int kz = tap / 9 - 1;
                const int ky = (tap / 3) % 3 - 1;
                const int kx = (tap % 3) - 1;
                const float z = (float)(zoA + kz) + offv[r][0];
                const float y = (float)(yoA + ky) + offv[r][1];
                const float x = (float)(xoA + kx) + offv[r][2];
                const float zf = floorf(z), yf = floorf(y), xf = floorf(x);
                const float fz = z - zf, fy = y - yf, fx = x - xf;
                const int z0i = (int)zf, y0i = (int)yf, x0i = (int)xf;

                const float wz0 = ((unsigned)z0i < DD) ? 1.f - fz : 0.f;
                const float wz1 = ((unsigned)(z0i + 1) < DD) ? fz : 0.f;
                const float wy0 = ((unsigned)y0i < DH) ? 1.f - fy : 0.f;
                const float wy1 = ((unsigned)(y0i + 1) < DH) ? fy : 0.f;
                const float wx0 = ((unsigned)x0i < DW) ? 1.f - fx : 0.f;
                const float wx1 = ((unsigned)(x0i + 1) < DW) ? fx : 0.f;
                float wcs[8];
                wcs[0] = wz0 * wy0 * wx0; wcs[1] = wz0 * wy0 * wx1;
                wcs[2] = wz0 * wy1 * wx0; wcs[3] = wz0 * wy1 * wx1;
                wcs[4] = wz1 * wy0 * wx0; wcs[5] = wz1 * wy0 * wx1;
                wcs[6] = wz1 * wy1 * wx0; wcs[7] = wz1 * wy1 * wx1;

                const int sz0 = z0i - (Z4 - 3);
                const int sy0 = y0i - (Y4 - 3);
                const int sx0 = x0i - (X4 - 3);

                __align__(16) __half2 acch[4];
#pragma unroll
                for (int rr = 0; rr < 4; ++rr) acch[rr] = __floats2half2_rn(0.f, 0.f);

                if ((unsigned)sz0 <= 7u && (unsigned)sy0 <= 8u &&
                    (unsigned)sx0 <= 8u) {
                    // LDS region gather, parity-swizzled half placement
                    const int v000 = (sz0 * 10 + sy0) * 10 + sx0;
                    const int s0 = (sx0 + sy0 + sz0 + h) & 1;   // base parity
                    const int s1 = s0 ^ 1;
                    const int vox[8] = {v000,       v000 + 1,
                                        v000 + 10,  v000 + 11,
                                        v000 + 100, v000 + 101,
                                        v000 + 110, v000 + 111};
                    const int sws[8] = {s0, s1, s1, s0, s1, s0, s0, s1};
                    half8 hv[8];
#pragma unroll
                    for (int ci = 0; ci < 8; ++ci)
                        hv[ci] = *(const half8*)(regB + vox[ci] * 32 + sws[ci] * 16);
#pragma unroll
                    for (int ci = 0; ci < 8; ++ci) {
                        const __half2 wh = __float2half2_rn(wcs[ci]);
                        const __half2* h2 = (const __half2*)&hv[ci];
#pragma unroll
                        for (int rr = 0; rr < 4; ++rr)
                            acch[rr] = __hfma2(h2[rr], wh, acch[rr]);
                    }
                } else {
                    // exact global fallback (rare)
                    const int iz0 = min(max(z0i, 0), DD - 1);
                    const int iz1 = min(max(z0i + 1, 0), DD - 1);
                    const int iy0 = min(max(y0i, 0), DH - 1);
                    const int iy1 = min(max(y0i + 1, 0), DH - 1);
                    const int ix0 = min(max(x0i, 0), DW - 1);
                    const int ix1 = min(max(x0i + 1, 0), DW - 1);
                    const int v000 = (iz0 << 10) + (iy0 << 5) + ix0;
                    const int dzo = (iz1 - iz0) << 10;
                    const int dyo = (iy1 - iy0) << 5;
                    const int dxo = ix1 - ix0;
                    const int vox[8] = {v000,             v000 + dxo,
                                        v000 + dyo,       v000 + dyo + dxo,
                                        v000 + dzo,       v000 + dzo + dxo,
                                        v000 + dzo + dyo, v000 + dzo + dyo + dxo};
                    const float4* baseF =
                        up4 + (size_t)((b * GG + g) * 2 + h) * PP;
#pragma unroll
                    for (int ci = 0; ci < 8; ++ci) {
                        const float4 u = baseF[vox[ci]];
                        const __half2 wh = __float2half2_rn(wcs[ci]);
                        const __half2* h2 = (const __half2*)&u;
#pragma unroll
                        for (int rr = 0; rr < 4; ++rr)
                            acch[rr] = __hfma2(h2[rr], wh, acch[rr]);
                    }
                }
                dbuf[(t2 * 2 + h) * SROW + tp + (tp >> 4)] = *(half8*)&acch[0];
            }

            // ---- A-prefetch for this round's MFMA: latency drains in barrier
            half8 Apre[4];
#pragma unroll
            for (int m = 0; m < 4; ++m)
                if (r * 4 + m < K3)
                    Apre[m] = wtx2[(size_t)((((g * 7 + r) * 4 + m) * 4 + ob) * 64 + l)];
            __syncthreads();

            // ---- MFMA: 32x32x16, wave tile 32o x 32p; 4 K-slices/round ----
            __builtin_amdgcn_s_setprio(1);
#pragma unroll
            for (int m = 0; m < 4; ++m) {
                if (r * 4 + m < K3) {
                    const int colg = pt * 32 + c31;
                    const half8 B = dbuf[(m * 2 + kh) * SROW + colg + (colg >> 4)];
                    acc = __builtin_amdgcn_mfma_f32_32x32x16_f16(Apre[m], B, acc, 0, 0, 0);
                }
            }
            __builtin_amdgcn_s_setprio(0);
        }
    }

    // ---- epilogue: ReLU + store (32x32 C/D layout) ----
    {
        const int cg = pt * 32 + c31;
        const int paddr = ((Z4 + (cg >> 4)) << 10) +
                          ((Y4 + ((cg >> 2) & 3)) << 5) + (X4 + (cg & 3));
#pragma unroll
        for (int reg = 0; reg < 16; ++reg) {
            const int row = (reg & 3) + 8 * (reg >> 2) + 4 * kh;
            const int o = ob * 32 + row;
            out[((size_t)(b * CDN + o) << 14) + paddr] = fmaxf(acc[reg], 0.f);
        }
    }
}

// ---------------------------------------------------------------------------
extern "C" void kernel_launch(void* const* d_in, const int* in_sizes, int n_in,
                              void* d_out, int out_size, void* d_ws, size_t ws_size,
                              hipStream_t stream)
{
    const float* src1x = (const float*)d_in[0];   // [2,128,8,16,16]
    const float* dst2x = (const float*)d_in[1];   // [2,128,16,32,32]
    const float* w_off = (const float*)d_in[2];   // [648,256]
    const float* w_dcn = (const float*)d_in[3];   // [128,128,3,3,3]
    float* out = (float*)d_out;

    char* ws = (char*)d_ws;
    half8* uph8 = (half8*)(ws);                    // 8,388,608 B
    half8* woxg = (half8*)(ws + 8388608);          //   393,216 B
    half8* wtx2 = (half8*)(ws + 8781824);          //   917,504 B

    prep_kernel<<<dim3(832), dim3(256), 0, stream>>>(
        src1x, w_off, w_dcn, uph8, woxg, wtx2);
    mega_kernel<<<dim3(256, BB), dim3(512), 0, stream>>>(
        dst2x, (const float4*)uph8, woxg, wtx2, out);
}

// Round 14
// 189.973 us; speedup vs baseline: 2.7279x; 1.0257x over previous
//
#include <hip/hip_runtime.h>
#include <hip/hip_fp16.h>
#include <math.h>

// Problem constants
#define BB   2
#define CSN  128
#define CDN  128
#define SD   8
#define SH   16
#define SW   16
#define DD   16
#define DH   32
#define DW   32
#define PP   (DD*DH*DW)   // 16384
#define GG   8
#define K3   27
#define OO   648

typedef _Float16 half8 __attribute__((ext_vector_type(8)));
typedef float f32x4 __attribute__((ext_vector_type(4)));
typedef float f32x16 __attribute__((ext_vector_type(16)));

// ---------------------------------------------------------------------------
// Kernel 1: PREP — upsample + weight packs.  R27: separable upsample —
// x-interp folded into staging (each thread x-upsamples its 16-value row
// in registers -> 32 values to LDS), so the read phase needs only y/z
// interp: 32 scalar LDS reads/output instead of 64.  Slab row stride 33
// (coprime 32): read banks (ys+xo) mod 32 -> 2-way (free).
// wtx2 packed for the 32x32x16 A-fragment layout (tap 27 zeros).
// ---------------------------------------------------------------------------
__global__ __launch_bounds__(256) void prep_kernel(
    const float* __restrict__ src, const float* __restrict__ wof,
    const float* __restrict__ wdcn, half8* __restrict__ uph8,
    half8* __restrict__ woxg, half8* __restrict__ wtx2)
{
    __shared__ float slab[2 * 8 * 16 * 33];   // zi, cc, ysrc, xup(+pad)
    const int bid = blockIdx.x;
    const int tid = threadIdx.x;

    if (bid < 512) {
        const int zo = bid & 15, pl = bid >> 4;
        const int h = pl & 1, g = (pl >> 1) & 7, b = pl >> 4;
        const int z0 = (zo - 1) >> 1;
        const float fz = (zo & 1) ? 0.25f : 0.75f;
        {
            const int zi = tid >> 7, cc = (tid >> 4) & 7, y = tid & 15;
            const int zsrc = min(max(z0 + zi, 0), SD - 1);
            const float* srow = src +
                (((size_t)(b * CSN + g * 16 + h * 8 + cc) * SD + zsrc) * SH + y) * SW;
            float r[16];
            *(float4*)&r[0]  = *(const float4*)(srow);
            *(float4*)&r[4]  = *(const float4*)(srow + 4);
            *(float4*)&r[8]  = *(const float4*)(srow + 8);
            *(float4*)&r[12] = *(const float4*)(srow + 12);
            float u[32];
#pragma unroll
            for (int xo = 0; xo < 32; ++xo) {
                const int x0 = (xo - 1) >> 1;
                const float fx = (xo & 1) ? 0.25f : 0.75f;
                const int xs0 = x0 < 0 ? 0 : x0;
                const int xs1 = (x0 + 1 > SW - 1) ? SW - 1 : x0 + 1;
                u[xo] = (1.f - fx) * r[xs0] + fx * r[xs1];
            }
            float* drow = &slab[((zi * 8 + cc) * 16 + y) * 33];
#pragma unroll
            for (int j = 0; j < 8; ++j)
                *(float4*)(drow + j * 4) = *(float4*)&u[j * 4];
        }
        __syncthreads();

        const float wz0 = 1.f - fz, wz1 = fz;
#pragma unroll
        for (int i = 0; i < 4; ++i) {
            const int pp = tid + i * 256;
            const int yo = pp >> 5, xo = pp & 31;
            const int y0 = (yo - 1) >> 1;
            const float fy = (yo & 1) ? 0.25f : 0.75f;
            const int ys0 = max(y0, 0), ys1 = min(y0 + 1, SH - 1);
            const int a0 = ys0 * 33 + xo, a1 = ys1 * 33 + xo;
            const float wy0 = 1.f - fy, wy1 = fy;

            half8 hv;
#pragma unroll
            for (int cc = 0; cc < 8; ++cc) {
                const float* pa = &slab[(cc * 16) * 33];
                const float* pb = &slab[((8 + cc) * 16) * 33];
                const float s0 = wy0 * pa[a0] + wy1 * pa[a1];
                const float s1 = wy0 * pb[a0] + wy1 * pb[a1];
                hv[cc] = (_Float16)(wz0 * s0 + wz1 * s1);
            }
            uph8[(size_t)pl * PP + zo * 1024 + pp] = hv;
        }
    } else if (bid < 608) {
        const int i = (bid - 512) * 256 + tid;     // < 24576
        const int q = i & 3, lo = (i >> 2) & 15;
        const int t6 = i >> 6;
        const int ot = t6 % 6;
        const int gc0 = t6 / 6;
        const int c0 = gc0 & 7, g = gc0 >> 3;
        const int m = ot * 16 + lo;
        half8 hv;
#pragma unroll
        for (int j = 0; j < 8; ++j) hv[j] = (_Float16)0.0f;
        if (m < 81) {
            const int o = g * 81 + m;
            const int c = c0 * 32 + q * 8;
            const float sc = (c >= 128) ? 2.0f : 1.0f;
            const float* wr = wof + (size_t)o * 256 + c;
#pragma unroll
            for (int j = 0; j < 8; ++j) hv[j] = (_Float16)(wr[j] * sc);
        }
        woxg[i] = hv;
    } else {
        const int i = (bid - 608) * 256 + tid;     // < 57344
        const int l = i & 63;
        const int ob = (i >> 6) & 3;
        const int m = (i >> 8) & 3;
        const int gr = i >> 10;                    // g*7 + r, < 56
        const int r = gr % 7, g = gr / 7;
        const int tap = r * 4 + m;
        half8 hv;
#pragma unroll
        for (int j = 0; j < 8; ++j) hv[j] = (_Float16)0.0f;
        if (tap < K3) {
            const int o = ob * 32 + (l & 31);
            const int cb = g * 16 + (l >> 5) * 8;
            const float* wr = wdcn + ((size_t)(o * CSN + cb)) * K3 + tap;
#pragma unroll
            for (int j = 0; j < 8; ++j) hv[j] = (_Float16)wr[(size_t)j * K3];
        }
        wtx2[i] = hv;
    }
}

// ---------------------------------------------------------------------------
// Kernel 2: MEGA — byte-identical to R26/R22 (session best: ~134 us mega).
// Structure: 4x4x4 cube/block, 512 thr, 2 blocks/CU; VGPR-roundtrip region
// staging (9x10x10, parity-swizzled); offls on dbuf1 (barrier-reduced
// schedule); offls stride 68; A-prefetch above the round barrier; setprio
// around MFMA clusters; DCN GEMM as 32x32x16 (4 B-reads/wave/round).
// Dead ends proven this session (do NOT retry): XCD swizzle on this
// fully-resident grid (R15), global_load_lds for scattered halo staging
// (R20), register state across divergent phase-A (R18), g-split partials
// (R14), 768-thr wide blocks (R24/R25: spill then 1-block residency).
// LDS: catx 32K | regB 28.8K | dbuf0 8.5K | dbuf1+ext = offls 11K
//   => 81296 B, 2 blocks/CU.
// ---------------------------------------------------------------------------
#define REGB_OFF 32768
#define SH2_OFF  61568
#define OFFLS_OFF 70272         // SH2_OFF + 544*16 (dbuf1 base)
#define LDS_TOTAL 81296
#define SROW 68                 // padded sampx row stride (half8)
#define OSTR 68                 // offls row stride (f16)

__global__ __launch_bounds__(512, 4) void mega_kernel(
    const float* __restrict__ dst, const float4* __restrict__ up4,
    const half8* __restrict__ woxg, const half8* __restrict__ wtx2,
    float* __restrict__ out)
{
    __shared__ __align__(16) char ldsraw[LDS_TOTAL];
    half8* catx = (half8*)ldsraw;
    char* regB = ldsraw + REGB_OFF;
    _Float16* offls = (_Float16*)(ldsraw + OFFLS_OFF);
    half8* sampx = (half8*)(ldsraw + SH2_OFF);   // dbuf: +0 / +544 half8

    const int tid = threadIdx.x;
    const int b = blockIdx.y;
    const int cb = blockIdx.x;
    const int X4 = (cb & 7) << 2, Y4 = ((cb >> 3) & 7) << 2, Z4 = (cb >> 6) << 2;

    // ---- phase 0: stage catx with cube columns ----
    {
        const int co = tid >> 4, pq = tid & 15;
        const int cz = pq >> 2, cy = pq & 3;
        const int pbase = ((Z4 + cz) << 10) + ((Y4 + cy) << 5) + X4;
        if (co < 16) {                      // dst channels, fp32 -> f16
            const int c = co * 8;
            const float* dp = dst + ((size_t)(b * CDN + c) << 14) + pbase;
            float vv[32];
#pragma unroll
            for (int j = 0; j < 8; ++j)
                *(float4*)&vv[j * 4] = *(const float4*)(dp + ((size_t)j << 14));
#pragma unroll
            for (int i = 0; i < 4; ++i) {
                half8 hh;
#pragma unroll
                for (int j = 0; j < 8; ++j) hh[j] = (_Float16)vv[j * 4 + i];
                catx[co * 64 + pq * 4 + i] = hh;
            }
        } else {                            // upsampled halves: f16 copy
            const int g2 = (co - 16) >> 1, oct = (co - 16) & 1;
            const half8* u8 = (const half8*)up4;
            const size_t base =
                ((size_t)((b * GG + g2) * 2 + oct) << 14) + pbase;
#pragma unroll
            for (int i = 0; i < 4; ++i)
                catx[co * 64 + pq * 4 + i] = u8[base + i];
        }
    }
    __syncthreads();    // catx ready for all g

    const int w = tid >> 6, l = tid & 63, lo = l & 15, q = l >> 4;
    const int t2 = w >> 1, h = w & 1;       // sampling: tap-in-round, ch-half
    const int ob = w & 3, pt = w >> 2;      // MFMA: o-block, p-block
    const int kh = l >> 5, c31 = l & 31;    // MFMA lane coords
    const int tp = l;                       // cube column
    const int cz = tp >> 4, cy = (tp >> 2) & 3, cx = tp & 3;
    const int zoA = Z4 + cz, yoA = Y4 + cy, xoA = X4 + cx;

    f32x16 acc;
#pragma unroll
    for (int i = 0; i < 16; ++i) acc[i] = 0.f;

#pragma unroll 1
    for (int g = 0; g < 8; ++g) {
        // (no top-of-g barrier: regB free after r=6 post-sample barrier;
        //  dbuf1/offls last read by r=5 MFMA which precedes it)

        // ---- region staging: interleaved (hf = c&1), parity-swizzled ----
#pragma unroll 1
        for (int c = tid; c < 1800; c += 512) {
            const int hf = c & 1;
            const int v = c >> 1;
            const int zz = v / 100, r2 = v - zz * 100;
            const int yy = r2 / 10, xx = r2 - yy * 10;
            const int vz = min(max(Z4 - 3 + zz, 0), DD - 1);
            const int vy = min(max(Y4 - 3 + yy, 0), DH - 1);
            const int vx = min(max(X4 - 3 + xx, 0), DW - 1);
            const float4 val =
                up4[(size_t)((b * GG + g) * 2 + hf) * PP +
                    (vz << 10) + (vy << 5) + vx];
            const int sw = (xx + yy + zz + hf) & 1;      // parity swizzle
            *(float4*)(regB + v * 32 + sw * 16) = val;
        }

        // ---- phase A: offset mini-GEMM, A reused across all 4 ps ----
        if (w < 6) {
            f32x4 a[4];
#pragma unroll
            for (int ps = 0; ps < 4; ++ps) a[ps] = (f32x4){0.f, 0.f, 0.f, 0.f};
            __builtin_amdgcn_s_setprio(1);
#pragma unroll
            for (int c0 = 0; c0 < 8; ++c0) {
                const half8 A =
                    woxg[(size_t)((((g * 8 + c0) * 6 + w) * 16 + lo) * 4 + q)];
#pragma unroll
                for (int ps = 0; ps < 4; ++ps) {
                    const half8 B = catx[(c0 * 4 + q) * 64 + ps * 16 + lo];
                    a[ps] = __builtin_amdgcn_mfma_f32_16x16x32_f16(A, B, a[ps], 0, 0, 0);
                }
            }
            __builtin_amdgcn_s_setprio(0);
#pragma unroll
            for (int ps = 0; ps < 4; ++ps) {
#pragma unroll
                for (int r = 0; r < 4; ++r) {
                    const int m = w * 16 + q * 4 + r;
                    if (m < 81)
                        offls[m * OSTR + ps * 16 + lo] = (_Float16)a[ps][r];
                }
            }
        }
        __syncthreads();    // staging + offls complete

        // ---- offsets -> registers (safe vs r=1 dbuf1 write: r=0 barrier) ----
        float offv[7][3];
#pragma unroll
        for (int r = 0; r < 7; ++r) {
            const int tap = r * 4 + t2;
            if (tap < K3) {
#pragma unroll
                for (int c = 0; c < 3; ++c)
                    offv[r][c] = (float)offls[(tap * 3 + c) * OSTR + tp];
            }
        }
        // (no post-offv barrier: r=0 writes dbuf0, disjoint from offls)

        // ---- 7 rounds x (sample 4 taps -> A-prefetch -> barrier -> MFMA) ----
#pragma unroll
        for (int r = 0; r < 7; ++r) {
            half8* dbuf = sampx + (r & 1) * 544;
            const int tap = r * 4 + t2;
            if (tap < K3) {
                const int kz = tap / 9 - 1;
                const int ky = (tap / 3) % 3 - 1;
                const int kx = (tap % 3) - 1;
                const float z = (float)(zoA + kz) + offv[r][0];
                const float y = (float)(yoA + ky) + offv[r][1];
                const float x = (float)(xoA + kx) + offv[r][2];
                const float zf = floorf(z), yf = floorf(y), xf = floorf(x);
                const float fz = z - zf, fy = y - yf, fx = x - xf;
                const int z0i = (int)zf, y0i = (int)yf, x0i = (int)xf;

                const float wz0 = ((unsigned)z0i < DD) ? 1.f - fz : 0.f;
                const float wz1 = ((unsigned)(z0i + 1) < DD) ? fz : 0.f;
                const float wy0 = ((unsigned)y0i < DH) ? 1.f - fy : 0.f;
                const float wy1 = ((unsigned)(y0i + 1) < DH) ? fy : 0.f;
                const float wx0 = ((unsigned)x0i < DW) ? 1.f - fx : 0.f;
                const float wx1 = ((unsigned)(x0i + 1) < DW) ? fx : 0.f;
                float wcs[8];
                wcs[0] = wz0 * wy0 * wx0; wcs[1] = wz0 * wy0 * wx1;
                wcs[2] = wz0 * wy1 * wx0; wcs[3] = wz0 * wy1 * wx1;
                wcs[4] = wz1 * wy0 * wx0; wcs[5] = wz1 * wy0 * wx1;
                wcs[6] = wz1 * wy1 * wx0; wcs[7] = wz1 * wy1 * wx1;

                const int sz0 = z0i - (Z4 - 3);
                const int sy0 = y0i - (Y4 - 3);
                const int sx0 = x0i - (X4 - 3);

                __align__(16) __half2 acch[4];
#pragma unroll
                for (int rr = 0; rr < 4; ++rr) acch[rr] = __floats2half2_rn(0.f, 0.f);

                if ((unsigned)sz0 <= 7u && (unsigned)sy0 <= 8u &&
                    (unsigned)sx0 <= 8u) {
                    // LDS region gather, parity-swizzled half placement
                    const int v000 = (sz0 * 10 + sy0) * 10 + sx0;
                    const int s0 = (sx0 + sy0 + sz0 + h) & 1;   // base parity
                    const int s1 = s0 ^ 1;
                    const int vox[8] = {v000,       v000 + 1,
                                        v000 + 10,  v000 + 11,
                                        v000 + 100, v000 + 101,
                                        v000 + 110, v000 + 111};
                    const int sws[8] = {s0, s1, s1, s0, s1, s0, s0, s1};
                    half8 hv[8];
#pragma unroll
                    for (int ci = 0; ci < 8; ++ci)
                        hv[ci] = *(const half8*)(regB + vox[ci] * 32 + sws[ci] * 16);
#pragma unroll
                    for (int ci = 0; ci < 8; ++ci) {
                        const __half2 wh = __float2half2_rn(wcs[ci]);
                        const __half2* h2 = (const __half2*)&hv[ci];
#pragma unroll
                        for (int rr = 0; rr < 4; ++rr)
                            acch[rr] = __hfma2(h2[rr], wh, acch[rr]);
                    }
                } else {
                    // exact global fallback (rare)
                    const int iz0 = min(max(z0i, 0), DD - 1);
                    const int iz1 = min(max(z0i + 1, 0), DD - 1);
                    const int iy0 = min(max(y0i, 0), DH - 1);
                    const int iy1 = min(max(y0i + 1, 0), DH - 1);
                    const int ix0 = min(max(x0i, 0), DW - 1);
                    const int ix1 = min(max(x0i + 1, 0), DW - 1);
                    const int v000 = (iz0 << 10) + (iy0 << 5) + ix0;
                    const int dzo = (iz1 - iz0) << 10;
                    const int dyo = (iy1 - iy0) << 5;
                    const int dxo = ix1 - ix0;
                    const int vox[8] = {v000,             v000 + dxo,
                                        v000 + dyo,       v000 + dyo + dxo,
                                        v000 + dzo,       v000 + dzo + dxo,
                                        v000 + dzo + dyo, v000 + dzo + dyo + dxo};
                    const float4* baseF =
                        up4 + (size_t)((b * GG + g) * 2 + h) * PP;
#pragma unroll
                    for (int ci = 0; ci < 8; ++ci) {
                        const float4 u = baseF[vox[ci]];
                        const __half2 wh = __float2half2_rn(wcs[ci]);
                        const __half2* h2 = (const __half2*)&u;
#pragma unroll
                        for (int rr = 0; rr < 4; ++rr)
                            acch[rr] = __hfma2(h2[rr], wh, acch[rr]);
                    }
                }
                dbuf[(t2 * 2 + h) * SROW + tp + (tp >> 4)] = *(half8*)&acch[0];
            }

            // ---- A-prefetch for this round's MFMA: latency drains in barrier
            half8 Apre[4];
#pragma unroll
            for (int m = 0; m < 4; ++m)
                if (r * 4 + m < K3)
                    Apre[m] = wtx2[(size_t)((((g * 7 + r) * 4 + m) * 4 + ob) * 64 + l)];
            __syncthreads();

            // ---- MFMA: 32x32x16, wave tile 32o x 32p; 4 K-slices/round ----
            __builtin_amdgcn_s_setprio(1);
#pragma unroll
            for (int m = 0; m < 4; ++m) {
                if (r * 4 + m < K3) {
                    const int colg = pt * 32 + c31;
                    const half8 B = dbuf[(m * 2 + kh) * SROW + colg + (colg >> 4)];
                    acc = __builtin_amdgcn_mfma_f32_32x32x16_f16(Apre[m], B, acc, 0, 0, 0);
                }
            }
            __builtin_amdgcn_s_setprio(0);
        }
    }

    // ---- epilogue: ReLU + store (32x32 C/D layout) ----
    {
        const int cg = pt * 32 + c31;
        const int paddr = ((Z4 + (cg >> 4)) << 10) +
                          ((Y4 + ((cg >> 2) & 3)) << 5) + (X4 + (cg & 3));
#pragma unroll
        for (int reg = 0; reg < 16; ++reg) {
            const int row = (reg & 3) + 8 * (reg >> 2) + 4 * kh;
            const int o = ob * 32 + row;
            out[((size_t)(b * CDN + o) << 14) + paddr] = fmaxf(acc[reg], 0.f);
        }
    }
}

// ---------------------------------------------------------------------------
extern "C" void kernel_launch(void* const* d_in, const int* in_sizes, int n_in,
                              void* d_out, int out_size, void* d_ws, size_t ws_size,
                              hipStream_t stream)
{
    const float* src1x = (const float*)d_in[0];   // [2,128,8,16,16]
    const float* dst2x = (const float*)d_in[1];   // [2,128,16,32,32]
    const float* w_off = (const float*)d_in[2];   // [648,256]
    const float* w_dcn = (const float*)d_in[3];   // [128,128,3,3,3]
    float* out = (float*)d_out;

    char* ws = (char*)d_ws;
    half8* uph8 = (half8*)(ws);                    // 8,388,608 B
    half8* woxg = (half8*)(ws + 8388608);          //   393,216 B
    half8* wtx2 = (half8*)(ws + 8781824);          //   917,504 B

    prep_kernel<<<dim3(832), dim3(256), 0, stream>>>(
        src1x, w_off, w_dcn, uph8, woxg, wtx2);
    mega_kernel<<<dim3(256, BB), dim3(512), 0, stream>>>(
        dst2x, (const float4*)uph8, woxg, wtx2, out);
}